// Round 15
// baseline (285.597 us; speedup 1.0000x reference)
//
#include <hip/hip_runtime.h>
#include <stdint.h>

// Problem constants (fixed by setup_inputs; all tensors f32)
#define B_ROWS 4096
#define D_IN   784
#define H_DIM  800
#define D_OUT  10
#define T_SIM  32
#define N_ELEM (B_ROWS * D_IN)   // 3211264
#define CAP    448               // spiking-list cap/row (mean ~376, sd ~14)

// ---------------------------------------------------------------------------
// Bit-exact JAX threefry2x32 (key = PRNGKey(42) = {0, 42})
// ---------------------------------------------------------------------------
__device__ __forceinline__ void threefry2x32(uint32_t k0, uint32_t k1,
                                             uint32_t& x0, uint32_t& x1) {
  uint32_t ks0 = k0, ks1 = k1, ks2 = k0 ^ k1 ^ 0x1BD11BDAu;
  x0 += ks0; x1 += ks1;
#define TF_RND(r) { x0 += x1; x1 = (x1 << (r)) | (x1 >> (32 - (r))); x1 ^= x0; }
  TF_RND(13) TF_RND(15) TF_RND(26) TF_RND(6)
  x0 += ks1; x1 += ks2 + 1u;
  TF_RND(17) TF_RND(29) TF_RND(16) TF_RND(24)
  x0 += ks2; x1 += ks0 + 2u;
  TF_RND(13) TF_RND(15) TF_RND(26) TF_RND(6)
  x0 += ks0; x1 += ks1 + 3u;
  TF_RND(17) TF_RND(29) TF_RND(16) TF_RND(24)
  x0 += ks1; x1 += ks2 + 4u;
  TF_RND(13) TF_RND(15) TF_RND(26) TF_RND(6)
  x0 += ks2; x1 += ks0 + 5u;
#undef TF_RND
}

// ---------------------------------------------------------------------------
// K0 (merged, R12): blocks [0,784) generate xfT[k][m] (k-major, same
// threefry counter i = m*784 + k -> bit-identical); blocks [784+) transpose
// W1.  Outputs independent -> order-safe; saves one launch.
// ---------------------------------------------------------------------------
__global__ __launch_bounds__(256) void prep(const float* __restrict__ x,
                                            const float* __restrict__ W1,
                                            float* __restrict__ xfT,
                                            float* __restrict__ W1T) {
  const int b = blockIdx.x;
  const int tid = threadIdx.x;
  if (b < 784) {
    const int m = (b & 15) * 256 + tid;           // 0..4095
    const int kb = (b >> 4) * 16;                 // 0,16,..,768
#pragma unroll 1
    for (int kk = 0; kk < 16; ++kk) {
      const int k = kb + kk;
      const int i = m * D_IN + k;
      uint32_t c0 = 0u, c1 = (uint32_t)i;
      threefry2x32(0u, 42u, c0, c1);
      uint32_t bits = c0 ^ c1;
      float u = __uint_as_float((bits >> 9) | 0x3F800000u) - 1.0f;
      xfT[(size_t)k * B_ROWS + m] = (u < x[i]) ? 1.0f : 0.0f;
    }
  } else {
    const int idx = (b - 784) * 256 + tid;        // over k*800+h
    if (idx < D_IN * H_DIM) {
      const int k = idx / H_DIM;
      const int h = idx - k * H_DIM;
      W1T[idx] = W1[h * D_IN + k];
    }
  }
}

// ---------------------------------------------------------------------------
// K1 (R15): R14's paired-tile core with BN=32, 128 threads, grid 25x64 =
// 1600 blocks = 6.25 barrier DOMAINS per CU (was 3.25).  Single moved
// variable: domain count.  Waves/CU stays 12.5 (R11's failure was halving
// residency at fixed grid); per-CU LDS demand stays ~98 us (32 b128/wave/
// tile, all 8-way broadcast conflict-free).  Hypothesis: the ~40-us gap
// over the LDS floor is drain windows with too few independent blocks to
// cover them; 2x domains -> drains of one block hide under compute of
// others.  H = 800 = 25*32 -> NO bounds checks anywhere.
// Pairing (R14, proven): 2 K-tiles per barrier, 25 barriers/block.
// Exactness: tile 2p fully consumed before 2p+1 -> globally ascending k,
// single f32 acc per output, identical fma chain + epilogue -> bit-exact.
// LDS 24 KB; VGPR ~60 at 128 thr.
// ---------------------------------------------------------------------------
#define BK 16

#define GL2LDS(g, l) __builtin_amdgcn_global_load_lds(                      \
    (const __attribute__((address_space(1))) void*)(g),                     \
    (__attribute__((address_space(3))) void*)(l), 16, 0, 0)

__global__ __launch_bounds__(128) void gemm_masks(const float* __restrict__ xfT,
                                                  const float* __restrict__ W1T,
                                                  const float* __restrict__ b1,
                                                  uint32_t* __restrict__ mb) {
  __shared__ __align__(16) float As[2][2][BK][64];   // [buf][sub], 16 KB
  __shared__ __align__(16) float Bs[2][2][BK][32];   // [buf][sub],  8 KB
  const int t  = threadIdx.x;        // 0..127
  const int tx = t & 7;              // h-group: 4 cols (8 groups)
  const int ty = t >> 3;             // m-group: 4 rows (16 groups)
  const int m0 = blockIdx.y * 64;
  const int n0 = blockIdx.x * 32;    // 25 * 32 = 800 exact

  // staging geometry (wave w = 0,1):
  //  A: rows 8w..8w+7 of the 16x64 tile as 2 slabs of 4 rows (1 KB each);
  //     lane l -> slab row +(l>>4), col (l&15)*4.
  //  B: rows 8w..8w+7 of the 16x32 tile as 1 slab (1 KB);
  //     lane l -> row 8w+(l>>3), col (l&7)*4.
  const int w = t >> 6;              // wave 0..1
  const int l = t & 63;              // lane
  const int sA0 = 8 * w + (l >> 4);
  const int sA1 = sA0 + 4;
  const int smA = (l & 15) * 4;
  const int sB  = 8 * w + (l >> 3);
  const int smB = (l & 7) * 4;
  const float* gA0 = xfT + (size_t)sA0 * B_ROWS + m0 + smA;  // + tt*16*4096
  const float* gA1 = xfT + (size_t)sA1 * B_ROWS + m0 + smA;
  const float* gB  = W1T + (size_t)sB  * H_DIM + n0 + smB;   // + tt*16*800

#define STAGE1(buf, sub, tt) {                                              \
    GL2LDS(gA0 + (size_t)(tt) * BK * B_ROWS, &As[buf][sub][8 * w][0]);      \
    GL2LDS(gA1 + (size_t)(tt) * BK * B_ROWS, &As[buf][sub][8 * w + 4][0]);  \
    GL2LDS(gB  + (size_t)(tt) * BK * H_DIM,  &Bs[buf][sub][8 * w][0]); }

#define COMPUTE(buf, sub) {                                                 \
    _Pragma("unroll")                                                       \
    for (int kk = 0; kk < BK; kk++) {                                       \
      float4 av = *(const float4*)&As[buf][sub][kk][ty * 4];                \
      float4 bv = *(const float4*)&Bs[buf][sub][kk][tx * 4];                \
      float a[4] = {av.x, av.y, av.z, av.w};                                \
      float b[4] = {bv.x, bv.y, bv.z, bv.w};                                \
      _Pragma("unroll")                                                     \
      for (int mi = 0; mi < 4; mi++)                                        \
        _Pragma("unroll")                                                   \
        for (int ni = 0; ni < 4; ni++)                                      \
          acc[mi][ni] = __builtin_fmaf(a[mi], b[ni], acc[mi][ni]);          \
    } }

  float acc[4][4] = {};
  // 49 tiles = 24 pairs (p=0..23) + tail tile 48 (p=24, sub 0 only)
  STAGE1(0, 0, 0);
  STAGE1(0, 1, 1);
  __syncthreads();                       // vmcnt(0) drain -> pair 0 ready

#pragma unroll 1
  for (int p = 0; p < 25; ++p) {
    const int cur = p & 1;
    if (p + 1 < 24) {                    // prefetch next full pair
      STAGE1(cur ^ 1, 0, 2 * p + 2);
      STAGE1(cur ^ 1, 1, 2 * p + 3);
    } else if (p + 1 == 24) {            // prefetch tail tile 48
      STAGE1(cur ^ 1, 0, 48);
    }
    COMPUTE(cur, 0);                     // tile 2p   (ascending k)
    if (p < 24) COMPUTE(cur, 1);         // tile 2p+1
    __syncthreads();                     // ONE barrier per pair
  }
#undef STAGE1
#undef COMPUTE

  // Epilogue: + b1 (f32 add like ref), exact f32 IF-period loop, emit mask32
  const int hOut = n0 + tx * 4;          // always < 800
  {
    float4 bb = *(const float4*)&b1[hOut];
#pragma unroll
    for (int mi = 0; mi < 4; mi++) {
      int m = m0 + ty * 4 + mi;
      float c4[4] = {acc[mi][0] + bb.x, acc[mi][1] + bb.y,
                     acc[mi][2] + bb.z, acc[mi][3] + bb.w};
      uint32_t mk4[4];
#pragma unroll
      for (int ni = 0; ni < 4; ni++) {
        float c = c4[ni];
        float v = 0.0f;
        int p2 = 0;
#pragma unroll 1
        for (int s = 1; s <= T_SIM; s++) {
          float h1 = v + c;                   // f32 add, as reference
          if (h1 >= 1.0f) { p2 = s; break; }
          v = h1;
        }
        uint32_t mk = 0;
        if (p2) for (int s = p2; s <= T_SIM; s += p2) mk |= 1u << (s - 1);
        mk4[ni] = mk;
      }
      *(uint4*)&mb[(size_t)m * H_DIM + hOut] =
          make_uint4(mk4[0], mk4[1], mk4[2], mk4[3]);
    }
  }
}

// ---------------------------------------------------------------------------
// K2 (R12 verbatim, ~112 us): 4 rows/block, 640 threads, paired pk reads
// (1 ds_read_b128 per 2 entries + 2 b64 w reads; all <=2-distinct).
// Exactness: ascending-h single-accumulator gated fold; pads mask=0;
// overflow -> gated full scan, same order.
// ---------------------------------------------------------------------------
__global__ __launch_bounds__(640) void snn_scan(const uint32_t* __restrict__ mb,
                                                const float* __restrict__ W2,
                                                const float* __restrict__ b2,
                                                float* __restrict__ out) {
  __shared__ __align__(16) float W2T[H_DIM * D_OUT];  // [h][o], 32000 B
  __shared__ __align__(16) uint2 pkS[4][CAP];         // {h*40, mask}, 14336 B
  __shared__ int   lenS[4];
  __shared__ float b2f[D_OUT];
  float* c2s = (float*)&pkS[0][0];            // union: [rr][t][o], 5120 B
  const int tid  = threadIdx.x;               // 0..639
  const int row0 = blockIdx.x * 4;

  if (tid < D_OUT) b2f[tid] = b2[tid];

  if (tid < 256) {
    // ---- Build (waves 0-3): ballot-compact mask words, ascending h ----
    const int r = tid >> 6, ln = tid & 63;    // r = row 0..3
    const uint64_t lm = (1ull << ln) - 1ull;
    const uint32_t* mrow = mb + (size_t)(row0 + r) * H_DIM;
    uint32_t mv[13];
#pragma unroll
    for (int ch = 0; ch < 13; ++ch) {         // independent coalesced loads
      int h = ch * 64 + ln;
      mv[ch] = (h < H_DIM) ? mrow[h] : 0u;
    }
    int off = 0;
#pragma unroll
    for (int ch = 0; ch < 13; ++ch) {
      bool g = (mv[ch] != 0u);
      uint64_t bal = __ballot(g);
      int pos = off + __popcll(bal & lm);
      if (g && pos < CAP) {
        uint2 pk; pk.x = (uint32_t)((ch * 64 + ln) * 40); pk.y = mv[ch];
        pkS[r][pos] = pk;
      }
      off += __popcll(bal);
    }
    if (off <= CAP) {                         // self-pad to multiple of 64
      int lp = (off + 63) & ~63;              // <= CAP since off <= CAP
      int i = off + ln;
      if (i < lp) { pkS[r][i].x = 0u; pkS[r][i].y = 0u; }
    }
    if (ln == 0) lenS[r] = off;
  } else {
    // ---- W2T staging (waves 4-9): coalesced read, LDS scatter ----
    for (int e = tid - 256; e < H_DIM * D_OUT; e += 384) {
      int o = e / H_DIM, h = e - o * H_DIM;
      W2T[h * D_OUT + o] = W2[e];
    }
  }
  __syncthreads();

  // ---- Exec: wave j: o-pair j%5, rows (j/5)*2 + lane-half ----
  float s0 = 0.0f, s1 = 0.0f;
  const int j  = tid >> 6;                    // 0..9
  const int jp = j % 5;                       // o-pair
  const int lane = tid & 63;
  const int t  = lane & 31;
  const int rr = (j / 5) * 2 + (lane >> 5);   // row 0..3
  const bool ovf = (lenS[0] > CAP) || (lenS[1] > CAP) ||
                   (lenS[2] > CAP) || (lenS[3] > CAP);
  {
    if (!ovf) {
      const int Lpad = (lenS[rr] + 63) & ~63; // per-row trip count (even)
      const uint2* pp = pkS[rr];
      const char* wbase = (const char*)W2T + 8 * jp;
#pragma unroll 4
      for (int i = 0; i < Lpad; i += 2) {
        uint4 pk2 = *(const uint4*)&pp[i];    // b128: 2 entries, 2-distinct
        float2 w0 = *(const float2*)(wbase + pk2.x);  // b64, 2-distinct
        float2 w1 = *(const float2*)(wbase + pk2.z);  // b64, 2-distinct
        bool g0 = (pk2.y >> t) & 1u;
        bool g1 = (pk2.w >> t) & 1u;
        s0 += g0 ? w0.x : 0.0f;               // entry i   (ascending h)
        s1 += g0 ? w0.y : 0.0f;
        s0 += g1 ? w1.x : 0.0f;               // entry i+1
        s1 += g1 ? w1.y : 0.0f;
      }
    } else {                                  // overflow fallback: gated scan
      const uint32_t* mrow = mb + (size_t)(row0 + rr) * H_DIM;
      const uint32_t vbit = 1u << t;
      const char* wbase = (const char*)W2T + 8 * jp;
      for (int h = 0; h < H_DIM; ++h) {
        uint32_t mk = mrow[h];
        float2 w = *(const float2*)(wbase + h * 40);
        s0 += (mk & vbit) ? w.x : 0.0f;
        s1 += (mk & vbit) ? w.y : 0.0f;
      }
    }
  }
  __syncthreads();                            // all pk reads complete
  c2s[((rr * T_SIM) + t) * D_OUT + 2 * jp]     = s0;   // union region write
  c2s[((rr * T_SIM) + t) * D_OUT + 2 * jp + 1] = s1;
  __syncthreads();

  // ---- Layer-2 IF scan + spike count (exact f32 ref order) ----
  if (tid < 4 * D_OUT) {
    const int rw = tid / D_OUT, o = tid % D_OUT;
    const float bb = b2f[o];
    float v = 0.0f; int cnt = 0;
#pragma unroll
    for (int tt = 0; tt < T_SIM; ++tt) {
      float cur2 = c2s[((rw * T_SIM) + tt) * D_OUT + o] + bb;  // f32 add
      float h2 = v + cur2;                    // f32 add
      bool spk = (h2 >= 1.0f);
      cnt += spk ? 1 : 0;
      v = spk ? 0.0f : h2;
    }
    out[(size_t)(row0 + rw) * D_OUT + o] = (float)cnt;
  }
}

// ---------------------------------------------------------------------------
extern "C" void kernel_launch(void* const* d_in, const int* in_sizes, int n_in,
                              void* d_out, int out_size, void* d_ws, size_t ws_size,
                              hipStream_t stream) {
  const float* x  = (const float*)d_in[0];
  const float* W1 = (const float*)d_in[1];
  const float* b1 = (const float*)d_in[2];
  const float* W2 = (const float*)d_in[3];
  const float* b2 = (const float*)d_in[4];
  float* outp = (float*)d_out;

  float*    xfT  = (float*)d_ws;                    // 784*4096 f32 (12.85 MB)
  float*    W1T  = xfT + (size_t)D_IN * B_ROWS;     // 784*800  f32 ( 2.51 MB)
  uint32_t* mbuf = (uint32_t*)(W1T + (size_t)D_IN * H_DIM);  // B*H u32 (13.1 MB)

  prep<<<784 + (D_IN * H_DIM + 255) / 256, 256, 0, stream>>>(x, W1, xfT, W1T);

  dim3 g1(25, 64);                                  // 25 x 64 = 1600 blocks
  gemm_masks<<<g1, 128, 0, stream>>>(xfT, W1T, b1, mbuf);

  snn_scan<<<B_ROWS / 4, 640, 0, stream>>>(mbuf, W2, b2, outp);
}

// Round 16
// 266.980 us; speedup vs baseline: 1.0697x; 1.0697x over previous
//
#include <hip/hip_runtime.h>
#include <stdint.h>

// Problem constants (fixed by setup_inputs; all tensors f32)
#define B_ROWS 4096
#define D_IN   784
#define H_DIM  800
#define D_OUT  10
#define T_SIM  32
#define N_ELEM (B_ROWS * D_IN)   // 3211264
#define CAP    448               // spiking-list cap/row (mean ~376, sd ~14)

// ---------------------------------------------------------------------------
// Bit-exact JAX threefry2x32 (key = PRNGKey(42) = {0, 42})
// ---------------------------------------------------------------------------
__device__ __forceinline__ void threefry2x32(uint32_t k0, uint32_t k1,
                                             uint32_t& x0, uint32_t& x1) {
  uint32_t ks0 = k0, ks1 = k1, ks2 = k0 ^ k1 ^ 0x1BD11BDAu;
  x0 += ks0; x1 += ks1;
#define TF_RND(r) { x0 += x1; x1 = (x1 << (r)) | (x1 >> (32 - (r))); x1 ^= x0; }
  TF_RND(13) TF_RND(15) TF_RND(26) TF_RND(6)
  x0 += ks1; x1 += ks2 + 1u;
  TF_RND(17) TF_RND(29) TF_RND(16) TF_RND(24)
  x0 += ks2; x1 += ks0 + 2u;
  TF_RND(13) TF_RND(15) TF_RND(26) TF_RND(6)
  x0 += ks0; x1 += ks1 + 3u;
  TF_RND(17) TF_RND(29) TF_RND(16) TF_RND(24)
  x0 += ks1; x1 += ks2 + 4u;
  TF_RND(13) TF_RND(15) TF_RND(26) TF_RND(6)
  x0 += ks2; x1 += ks0 + 5u;
#undef TF_RND
}

// ---------------------------------------------------------------------------
// K0 (merged): blocks [0,784) generate xfT[k][m]; blocks [784,3234)
// transpose W1 (2450*256 = 627200 exact); blocks [3234,3266) transpose W2
// into W2TG[h*10+o] (8000 elems).  All outputs independent -> order-safe.
// ---------------------------------------------------------------------------
__global__ __launch_bounds__(256) void prep(const float* __restrict__ x,
                                            const float* __restrict__ W1,
                                            const float* __restrict__ W2,
                                            float* __restrict__ xfT,
                                            float* __restrict__ W1T,
                                            float* __restrict__ W2TG) {
  const int b = blockIdx.x;
  const int tid = threadIdx.x;
  if (b < 784) {
    const int m = (b & 15) * 256 + tid;           // 0..4095
    const int kb = (b >> 4) * 16;                 // 0,16,..,768
#pragma unroll 1
    for (int kk = 0; kk < 16; ++kk) {
      const int k = kb + kk;
      const int i = m * D_IN + k;
      uint32_t c0 = 0u, c1 = (uint32_t)i;
      threefry2x32(0u, 42u, c0, c1);
      uint32_t bits = c0 ^ c1;
      float u = __uint_as_float((bits >> 9) | 0x3F800000u) - 1.0f;
      xfT[(size_t)k * B_ROWS + m] = (u < x[i]) ? 1.0f : 0.0f;
    }
  } else if (b < 3234) {
    const int idx = (b - 784) * 256 + tid;        // over k*800+h, exact
    const int k = idx / H_DIM;
    const int h = idx - k * H_DIM;
    W1T[idx] = W1[h * D_IN + k];
  } else {
    const int idx = (b - 3234) * 256 + tid;       // h*10+o
    if (idx < H_DIM * D_OUT) {
      const int h = idx / D_OUT;
      const int o = idx - h * D_OUT;
      W2TG[idx] = W2[o * H_DIM + h];
    }
  }
}

// ---------------------------------------------------------------------------
// K1 (R14 VERBATIM, measured 142.3 us — floor of 9 structural variants):
// 64x64/4x4, 256 thr, async global_load_lds, TWO K-tiles per barrier
// (25 barriers).  Exactness: tile 2p fully consumed before 2p+1 ->
// globally ascending k, single f32 acc per output, identical fma chain +
// epilogue -> bit-exact.
// ---------------------------------------------------------------------------
#define BK 16

#define GL2LDS(g, l) __builtin_amdgcn_global_load_lds(                      \
    (const __attribute__((address_space(1))) void*)(g),                     \
    (__attribute__((address_space(3))) void*)(l), 16, 0, 0)

__global__ __launch_bounds__(256) void gemm_masks(const float* __restrict__ xfT,
                                                  const float* __restrict__ W1T,
                                                  const float* __restrict__ b1,
                                                  uint32_t* __restrict__ mb) {
  __shared__ __align__(16) float As[2][2][BK][64];   // [buf][sub], 16 KB
  __shared__ __align__(16) float Bs[2][2][BK][64];   // [buf][sub], 16 KB
  const int t  = threadIdx.x;        // 0..255
  const int tx = t & 15, ty = t >> 4;
  const int m0 = blockIdx.y * 64;
  const int n0 = blockIdx.x * 64;

  // staging geometry: wave w stages rows 4w..4w+3 of each 16x64 tile
  const int w = t >> 6;              // wave 0..3
  const int l = t & 63;              // lane
  const int skk = 4 * w + (l >> 4);  // source row 0..15
  const int sm  = (l & 15) * 4;      // source col group
  const float* gA = xfT + (size_t)skk * B_ROWS + m0 + sm;  // + tt*16*4096
  const float* gB = W1T + (size_t)skk * H_DIM + n0 + sm;   // + tt*16*800

#define STAGE1(buf, sub, tt) {                                              \
    GL2LDS(gA + (size_t)(tt) * BK * B_ROWS, &As[buf][sub][4 * w][0]);       \
    GL2LDS(gB + (size_t)(tt) * BK * H_DIM,  &Bs[buf][sub][4 * w][0]); }

#define COMPUTE(buf, sub) {                                                 \
    _Pragma("unroll")                                                       \
    for (int kk = 0; kk < BK; kk++) {                                       \
      float4 av = *(const float4*)&As[buf][sub][kk][ty * 4];                \
      float4 bv = *(const float4*)&Bs[buf][sub][kk][tx * 4];                \
      float a[4] = {av.x, av.y, av.z, av.w};                                \
      float b[4] = {bv.x, bv.y, bv.z, bv.w};                                \
      _Pragma("unroll")                                                     \
      for (int mi = 0; mi < 4; mi++)                                        \
        _Pragma("unroll")                                                   \
        for (int ni = 0; ni < 4; ni++)                                      \
          acc[mi][ni] = __builtin_fmaf(a[mi], b[ni], acc[mi][ni]);          \
    } }

  float acc[4][4] = {};
  // 49 tiles = 24 pairs (p=0..23) + tail tile 48 (p=24, sub 0 only)
  STAGE1(0, 0, 0);
  STAGE1(0, 1, 1);
  __syncthreads();                       // vmcnt(0) drain -> pair 0 ready

#pragma unroll 1
  for (int p = 0; p < 25; ++p) {
    const int cur = p & 1;
    if (p + 1 < 24) {                    // prefetch next full pair
      STAGE1(cur ^ 1, 0, 2 * p + 2);
      STAGE1(cur ^ 1, 1, 2 * p + 3);
    } else if (p + 1 == 24) {            // prefetch tail tile 48
      STAGE1(cur ^ 1, 0, 48);
    }
    COMPUTE(cur, 0);                     // tile 2p   (ascending k)
    if (p < 24) COMPUTE(cur, 1);         // tile 2p+1
    __syncthreads();                     // ONE barrier per pair
  }
#undef STAGE1
#undef COMPUTE

  // Epilogue: + b1 (f32 add like ref), exact f32 IF-period loop, emit mask32
  const int hOut = n0 + tx * 4;          // multiple of 4
  if (hOut < H_DIM) {
    float4 bb = *(const float4*)&b1[hOut];
#pragma unroll
    for (int mi = 0; mi < 4; mi++) {
      int m = m0 + ty * 4 + mi;
      float c4[4] = {acc[mi][0] + bb.x, acc[mi][1] + bb.y,
                     acc[mi][2] + bb.z, acc[mi][3] + bb.w};
      uint32_t mk4[4];
#pragma unroll
      for (int ni = 0; ni < 4; ni++) {
        float c = c4[ni];
        float v = 0.0f;
        int p2 = 0;
#pragma unroll 1
        for (int s = 1; s <= T_SIM; s++) {
          float h1 = v + c;                   // f32 add, as reference
          if (h1 >= 1.0f) { p2 = s; break; }
          v = h1;
        }
        uint32_t mk = 0;
        if (p2) for (int s = p2; s <= T_SIM; s += p2) mk |= 1u << (s - 1);
        mk4[ni] = mk;
      }
      *(uint4*)&mb[(size_t)m * H_DIM + hOut] =
          make_uint4(mk4[0], mk4[1], mk4[2], mk4[3]);
    }
  }
}

// ---------------------------------------------------------------------------
// K2 (R16): R12's exec loop verbatim; W2T staging replaced by ~32
// global_load_lds width-16 from the prep-transposed W2TG (L2-resident).
// Old staging: 8000 scalar loads + 8000 scattered ds_writes per block
// (~21 iters x ~6 instrs on 384 threads) -> now 6 staging waves x 5-6
// linear 1-KB slab copies.  W2T padded to 32768 B (slab 31 stages 256 B of
// garbage past float 8000 — never read: pk.x+8 <= 32000).  LDS ~47.2 KB ->
// still 3 blocks/CU.  Exec, fold order, pads, overflow: byte-identical ->
// bit-exact.
// ---------------------------------------------------------------------------
__global__ __launch_bounds__(640) void snn_scan(const uint32_t* __restrict__ mb,
                                                const float* __restrict__ W2TG,
                                                const float* __restrict__ b2,
                                                float* __restrict__ out) {
  __shared__ __align__(16) float W2T[8192];           // [h][o] + pad, 32768 B
  __shared__ __align__(16) uint2 pkS[4][CAP];         // {h*40, mask}, 14336 B
  __shared__ int   lenS[4];
  __shared__ float b2f[D_OUT];
  float* c2s = (float*)&pkS[0][0];            // union: [rr][t][o], 5120 B
  const int tid  = threadIdx.x;               // 0..639
  const int row0 = blockIdx.x * 4;

  if (tid < D_OUT) b2f[tid] = b2[tid];

  if (tid < 256) {
    // ---- Build (waves 0-3): ballot-compact mask words, ascending h ----
    const int r = tid >> 6, ln = tid & 63;    // r = row 0..3
    const uint64_t lm = (1ull << ln) - 1ull;
    const uint32_t* mrow = mb + (size_t)(row0 + r) * H_DIM;
    uint32_t mv[13];
#pragma unroll
    for (int ch = 0; ch < 13; ++ch) {         // independent coalesced loads
      int h = ch * 64 + ln;
      mv[ch] = (h < H_DIM) ? mrow[h] : 0u;
    }
    int off = 0;
#pragma unroll
    for (int ch = 0; ch < 13; ++ch) {
      bool g = (mv[ch] != 0u);
      uint64_t bal = __ballot(g);
      int pos = off + __popcll(bal & lm);
      if (g && pos < CAP) {
        uint2 pk; pk.x = (uint32_t)((ch * 64 + ln) * 40); pk.y = mv[ch];
        pkS[r][pos] = pk;
      }
      off += __popcll(bal);
    }
    if (off <= CAP) {                         // self-pad to multiple of 64
      int lp = (off + 63) & ~63;              // <= CAP since off <= CAP
      int i = off + ln;
      if (i < lp) { pkS[r][i].x = 0u; pkS[r][i].y = 0u; }
    }
    if (ln == 0) lenS[r] = off;
  } else {
    // ---- W2T staging (waves 4-9): 32 linear 1-KB slabs, async ----
    const int sw = (tid >> 6) - 4;            // staging wave 0..5
    const int lo = (tid & 63) * 16;           // per-lane byte offset in slab
#pragma unroll 1
    for (int s = sw; s < 32; s += 6) {
      GL2LDS((const char*)W2TG + s * 1024 + lo, (char*)W2T + s * 1024);
    }
  }
  __syncthreads();                            // drains vmcnt -> W2T ready

  // ---- Exec: wave j: o-pair j%5, rows (j/5)*2 + lane-half ----
  float s0 = 0.0f, s1 = 0.0f;
  const int j  = tid >> 6;                    // 0..9
  const int jp = j % 5;                       // o-pair
  const int lane = tid & 63;
  const int t  = lane & 31;
  const int rr = (j / 5) * 2 + (lane >> 5);   // row 0..3
  const bool ovf = (lenS[0] > CAP) || (lenS[1] > CAP) ||
                   (lenS[2] > CAP) || (lenS[3] > CAP);
  {
    if (!ovf) {
      const int Lpad = (lenS[rr] + 63) & ~63; // per-row trip count (even)
      const uint2* pp = pkS[rr];
      const char* wbase = (const char*)W2T + 8 * jp;
#pragma unroll 4
      for (int i = 0; i < Lpad; i += 2) {
        uint4 pk2 = *(const uint4*)&pp[i];    // b128: 2 entries, 2-distinct
        float2 w0 = *(const float2*)(wbase + pk2.x);  // b64, 2-distinct
        float2 w1 = *(const float2*)(wbase + pk2.z);  // b64, 2-distinct
        bool g0 = (pk2.y >> t) & 1u;
        bool g1 = (pk2.w >> t) & 1u;
        s0 += g0 ? w0.x : 0.0f;               // entry i   (ascending h)
        s1 += g0 ? w0.y : 0.0f;
        s0 += g1 ? w1.x : 0.0f;               // entry i+1
        s1 += g1 ? w1.y : 0.0f;
      }
    } else {                                  // overflow fallback: gated scan
      const uint32_t* mrow = mb + (size_t)(row0 + rr) * H_DIM;
      const uint32_t vbit = 1u << t;
      const char* wbase = (const char*)W2T + 8 * jp;
      for (int h = 0; h < H_DIM; ++h) {
        uint32_t mk = mrow[h];
        float2 w = *(const float2*)(wbase + h * 40);
        s0 += (mk & vbit) ? w.x : 0.0f;
        s1 += (mk & vbit) ? w.y : 0.0f;
      }
    }
  }
  __syncthreads();                            // all pk reads complete
  c2s[((rr * T_SIM) + t) * D_OUT + 2 * jp]     = s0;   // union region write
  c2s[((rr * T_SIM) + t) * D_OUT + 2 * jp + 1] = s1;
  __syncthreads();

  // ---- Layer-2 IF scan + spike count (exact f32 ref order) ----
  if (tid < 4 * D_OUT) {
    const int rw = tid / D_OUT, o = tid % D_OUT;
    const float bb = b2f[o];
    float v = 0.0f; int cnt = 0;
#pragma unroll
    for (int tt = 0; tt < T_SIM; ++tt) {
      float cur2 = c2s[((rw * T_SIM) + tt) * D_OUT + o] + bb;  // f32 add
      float h2 = v + cur2;                    // f32 add
      bool spk = (h2 >= 1.0f);
      cnt += spk ? 1 : 0;
      v = spk ? 0.0f : h2;
    }
    out[(size_t)(row0 + rw) * D_OUT + o] = (float)cnt;
  }
}

// ---------------------------------------------------------------------------
extern "C" void kernel_launch(void* const* d_in, const int* in_sizes, int n_in,
                              void* d_out, int out_size, void* d_ws, size_t ws_size,
                              hipStream_t stream) {
  const float* x  = (const float*)d_in[0];
  const float* W1 = (const float*)d_in[1];
  const float* b1 = (const float*)d_in[2];
  const float* W2 = (const float*)d_in[3];
  const float* b2 = (const float*)d_in[4];
  float* outp = (float*)d_out;

  float*    xfT  = (float*)d_ws;                    // 784*4096 f32 (12.85 MB)
  float*    W1T  = xfT + (size_t)D_IN * B_ROWS;     // 784*800  f32 ( 2.51 MB)
  float*    W2TG = W1T + (size_t)D_IN * H_DIM;      // 8192 f32 (32 KB + pad)
  uint32_t* mbuf = (uint32_t*)(W2TG + 8192);        // B*H u32 (13.1 MB)

  prep<<<3266, 256, 0, stream>>>(x, W1, W2, xfT, W1T, W2TG);

  dim3 g1(13, 64);                                  // 13 x 64 = 832 blocks
  gemm_masks<<<g1, 256, 0, stream>>>(xfT, W1T, b1, mbuf);

  snn_scan<<<B_ROWS / 4, 640, 0, stream>>>(mbuf, W2TG, b2, outp);
}